// Round 14
// baseline (89.519 us; speedup 1.0000x reference)
//
#include <hip/hip_runtime.h>
#include <math.h>

// NeuralMemory: chunked-parallel decaying rank-1 memory scan, all-MFMA version.
//   S_t = decay*S_{t-1} + s_t * v_t k_t^T ;  out_t = q_t^T S_{t-1}
// Chunk C=128, NC=16, b=4, s=2048, d_model=1024, d_mem=256.
//
//  1. prep:   x -> x16 ; gate = sigmoid(x@Wg+bg) ; Wk|Wv|Wq -> w16 ; Wo -> wot16
//  2. proj:   64x64-tile MFMA, BK=64 (1536 blocks, 6/CU): v16, qd16 = bf16(x@W + b);
//             epilogue LDS-transposes k/v quarter-tiles -> kT16/vTw16 (gate-folded)
//  3. mid:    ONE launch, 320 blocks: [0,256) Ut16[z] quadrants = kT @ vTw^T;
//             [256,320) scores A16[z] = mask(qd@v^T)*gate  (independent work overlapped)
//  4. scan:   T16[z] = bf16(S_c^T) running over chunks; writes final_state (x8 vectorized)
//  5. attn2:  mo16 = qd@T^T + A16@kT^T   (per nh,rh,z; 256 blocks)
//  6. y64:    64x64-tile MFMA (2048 blocks, 8/CU): out_y = mo16 @ wot16^T + bo

using bf16x8 = __attribute__((ext_vector_type(8))) short;
using f32x4  = __attribute__((ext_vector_type(4))) float;
using u16x4  = __attribute__((ext_vector_type(4))) unsigned short;
using u16x8  = __attribute__((ext_vector_type(8))) unsigned short;

__device__ inline unsigned short f2bf(float f) {
  unsigned int u = __float_as_uint(f);
  u = (u + 0x7FFF + ((u >> 16) & 1)) >> 16;
  return (unsigned short)u;
}
__device__ inline float bf2f(unsigned short u) {
  return __uint_as_float(((unsigned int)u) << 16);
}

#define GLD_LDS(gsrc, ldst) \
  __builtin_amdgcn_global_load_lds( \
      (const __attribute__((address_space(1))) unsigned int*)(gsrc), \
      (__attribute__((address_space(3))) unsigned int*)(ldst), 16, 0, 0)

// ---------------------------------------------------------------- proj (64x64 tile, BK=64)
// Grid 1536 (XCD-swizzled): bn in [0,12): sel=bn>>2 (k/v/q), qtr=bn&3 (64-col quarter);
// bm in [0,128): 64-row slab (chunk z = bm>>1, j-half = bm&1). 4 waves x 16 cols.
__global__ __launch_bounds__(256)
void proj_kernel(const unsigned short* __restrict__ x16, const unsigned short* __restrict__ w16,
                 const float* __restrict__ bk, const float* __restrict__ bv,
                 const float* __restrict__ bq, const float* __restrict__ gate,
                 const float* __restrict__ decay_ptr,
                 unsigned short* __restrict__ o_v, unsigned short* __restrict__ o_qd,
                 unsigned short* __restrict__ o_kT, unsigned short* __restrict__ o_vTw) {
  __shared__ unsigned short As[64 * 64];    // 8KB; reused as 64x64 transpose buf
  __shared__ unsigned short Bs[64 * 64];    // 8KB
  __shared__ float warr[64];
  const int tid = threadIdx.x;
  const int bid = (blockIdx.x & 7) * (gridDim.x >> 3) + (blockIdx.x >> 3);
  const int bn = bid % 12, bm = bid / 12;
  const int m0 = bm * 64, n0 = bn * 64;
  const int lane = tid & 63, wv = tid >> 6;
  const int srow = tid >> 3, scol = (tid & 7) * 8;   // 128B LDS rows: lane-linear

  f32x4 acc[4] = {};
  const unsigned short* Abase = x16 + (long long)m0 * 1024;
  const unsigned short* Bbase = w16 + (long long)n0 * 1024;

  for (int k0 = 0; k0 < 1024; k0 += 64) {
    if (k0) __syncthreads();
#pragma unroll
    for (int i = 0; i < 2; i++) {
      int row = i * 32 + srow;
      GLD_LDS(Abase + (long long)row * 1024 + k0 + scol, &As[row * 64 + scol]);
      GLD_LDS(Bbase + (long long)row * 1024 + k0 + scol, &Bs[row * 64 + scol]);
    }
    __syncthreads();
#pragma unroll
    for (int kk = 0; kk < 2; kk++) {
      const int kb = kk * 32 + 8 * (lane >> 4);
      bf16x8 bfr = *(const bf16x8*)&Bs[(wv * 16 + (lane & 15)) * 64 + kb];
#pragma unroll
      for (int m = 0; m < 4; m++) {
        bf16x8 af = *(const bf16x8*)&As[(m * 16 + (lane & 15)) * 64 + kb];
        acc[m] = __builtin_amdgcn_mfma_f32_16x16x32_bf16(af, bfr, acc[m], 0, 0, 0);
      }
    }
  }

  const float log2d = log2f(decay_ptr[0]);
  const int sel = bn >> 2;        // 0:k 1:v 2:q
  const int qtr = bn & 3;         // 64-col quarter of d_mem
  const int z = bm >> 1, jbase = (bm & 1) * 64;

  if (sel < 2) {
    __syncthreads();              // all waves done with As/Bs fragments
    if (sel == 1 && tid < 64)
      warr[tid] = gate[z * 128 + jbase + tid] * exp2f((float)(127 - (jbase + tid)) * log2d);
  }

  const int cl = wv * 16 + (lane & 15);   // local col 0..63
  const int d = qtr * 64 + cl;            // d_mem index
  const float bias = (sel == 0) ? bk[d] : (sel == 1) ? bv[d] : bq[d];
#pragma unroll
  for (int m = 0; m < 4; m++) {
    int r0 = m * 16 + (lane >> 4) * 4;    // local row base 0..63
    if (sel < 2) {
      u16x4 pk;
#pragma unroll
      for (int q = 0; q < 4; q++) {
        float v = acc[m][q] + bias;
        pk[q] = f2bf(v);
        if (sel == 1)
          o_v[((long long)m0 + r0 + q) * 256 + d] = pk[q];
      }
      int byteoff = (cl * 128 + r0 * 2) ^ ((cl & 7) << 4);
      *(u16x4*)((char*)As + byteoff) = pk;
    } else {
#pragma unroll
      for (int q = 0; q < 4; q++) {
        long long row = m0 + r0 + q;
        float v = acc[m][q] + bias;
        o_qd[row * 256 + d] = f2bf(v * exp2f((float)(jbase + r0 + q) * log2d));
      }
    }
  }

  if (sel < 2) {
    __syncthreads();
    unsigned short* dst = (sel == 0 ? o_kT : o_vTw) + (long long)z * 32768;
#pragma unroll
    for (int pp = 0; pp < 2; pp++) {
      int idx = pp * 256 + tid;    // 0..511
      int c = idx >> 3;            // local col (d) 0..63
      int j0 = (idx & 7) * 8;      // row-run start 0..56
      u16x8 o = *(const u16x8*)((char*)As + ((c * 128 + j0 * 2) ^ ((c & 7) << 4)));
      if (sel == 1) {
#pragma unroll
        for (int t = 0; t < 8; t++) o[t] = f2bf(bf2f(o[t]) * warr[j0 + t]);
      }
      *(u16x8*)&dst[(long long)(qtr * 64 + c) * 128 + jbase + j0] = o;
    }
  }
}

// ---------------------------------------------------------------- mid: Ut quadrants + scores
// Grid 320 x 256thr. bid<256: Ut quadrant (z=bid>>2, bm=(bid>>1)&1, bn=bid&1).
// bid>=256: scores chunk z=bid-256: A16[z][i][j] = (i>j) ? (qd_i.v_j)*s_j*d^{-(j+1)} : 0.
__global__ __launch_bounds__(256)
void mid_kernel(const unsigned short* __restrict__ kT16, const unsigned short* __restrict__ vTw16,
                unsigned short* __restrict__ Ut16,
                const unsigned short* __restrict__ qd16, const unsigned short* __restrict__ v16,
                unsigned short* __restrict__ A16, const float* __restrict__ gbuf,
                const float* __restrict__ decay_ptr) {
  __shared__ unsigned short As[128 * 64];
  __shared__ unsigned short Bs[128 * 64];
  const int tid = threadIdx.x, lane = tid & 63, wv = tid >> 6;
  const int wr = wv >> 1, wc = wv & 1;
  const int srow = tid >> 3, scol = (tid & 7) * 8;
  f32x4 acc[4][4] = {};

  if (blockIdx.x < 256) {
    // ---------------- Ut quadrant ----------------
    const int b = blockIdx.x;
    const int z = b >> 2, bm = (b >> 1) & 1, bn = b & 1;
    const unsigned short* Abase = kT16 + (long long)z * 32768 + (long long)(bm * 128) * 128;
    const unsigned short* Bbase = vTw16 + (long long)z * 32768 + (long long)(bn * 128) * 128;
    for (int k0 = 0; k0 < 128; k0 += 64) {
      if (k0) __syncthreads();
#pragma unroll
      for (int i = 0; i < 4; i++) {
        int row = i * 32 + srow;
        GLD_LDS(Abase + (long long)row * 128 + k0 + scol, &As[row * 64 + scol]);
        GLD_LDS(Bbase + (long long)row * 128 + k0 + scol, &Bs[row * 64 + scol]);
      }
      __syncthreads();
#pragma unroll
      for (int kk = 0; kk < 2; kk++) {
        const int kb = kk * 32 + 8 * (lane >> 4);
        bf16x8 af[4], bfr[4];
#pragma unroll
        for (int m = 0; m < 4; m++)
          af[m] = *(const bf16x8*)&As[(wr * 64 + m * 16 + (lane & 15)) * 64 + kb];
#pragma unroll
        for (int n = 0; n < 4; n++)
          bfr[n] = *(const bf16x8*)&Bs[(wc * 64 + n * 16 + (lane & 15)) * 64 + kb];
#pragma unroll
        for (int m = 0; m < 4; m++)
#pragma unroll
          for (int n = 0; n < 4; n++)
            acc[m][n] = __builtin_amdgcn_mfma_f32_16x16x32_bf16(af[m], bfr[n], acc[m][n], 0, 0, 0);
      }
    }
    unsigned short* out = Ut16 + (long long)z * 65536;
#pragma unroll
    for (int m = 0; m < 4; m++) {
#pragma unroll
      for (int n = 0; n < 4; n++) {
        int col = bn * 128 + wc * 64 + n * 16 + (lane & 15);
#pragma unroll
        for (int q = 0; q < 4; q++) {
          int row = bm * 128 + wr * 64 + m * 16 + (lane >> 4) * 4 + q;
          out[(long long)row * 256 + col] = f2bf(acc[m][n][q]);
        }
      }
    }
  } else {
    // ---------------- scores ----------------
    const int z = blockIdx.x - 256;
    const unsigned short* Abase = qd16 + (long long)z * 32768;   // [128][256]
    const unsigned short* Bbase = v16 + (long long)z * 32768;
    for (int k0 = 0; k0 < 256; k0 += 64) {
      if (k0) __syncthreads();
#pragma unroll
      for (int i = 0; i < 4; i++) {
        int row = i * 32 + srow;
        GLD_LDS(Abase + (long long)row * 256 + k0 + scol, &As[row * 64 + scol]);
        GLD_LDS(Bbase + (long long)row * 256 + k0 + scol, &Bs[row * 64 + scol]);
      }
      __syncthreads();
#pragma unroll
      for (int kk = 0; kk < 2; kk++) {
        const int kb = kk * 32 + 8 * (lane >> 4);
        bf16x8 af[4], bfr[4];
#pragma unroll
        for (int m = 0; m < 4; m++)
          af[m] = *(const bf16x8*)&As[(wr * 64 + m * 16 + (lane & 15)) * 64 + kb];
#pragma unroll
        for (int n = 0; n < 4; n++)
          bfr[n] = *(const bf16x8*)&Bs[(wc * 64 + n * 16 + (lane & 15)) * 64 + kb];
#pragma unroll
        for (int m = 0; m < 4; m++)
#pragma unroll
          for (int n = 0; n < 4; n++)
            acc[m][n] = __builtin_amdgcn_mfma_f32_16x16x32_bf16(af[m], bfr[n], acc[m][n], 0, 0, 0);
      }
    }
    const float log2d = log2f(decay_ptr[0]);
    unsigned short* out = A16 + (long long)z * 16384;
#pragma unroll
    for (int n = 0; n < 4; n++) {
      int col = wc * 64 + n * 16 + (lane & 15);       // j
      float gsc = gbuf[z * 128 + col] * exp2f(-(float)(col + 1) * log2d);
#pragma unroll
      for (int m = 0; m < 4; m++) {
#pragma unroll
        for (int q = 0; q < 4; q++) {
          int row = wr * 64 + m * 16 + (lane >> 4) * 4 + q;   // i
          float v = (col < row) ? acc[m][n][q] * gsc : 0.f;
          out[(long long)row * 128 + col] = f2bf(v);
        }
      }
    }
  }
}

// ---------------------------------------------------------------- attn2: mo = qd@T^T + A@kT^T
// Block (nh, rh, z): rows roff..roff+64 of chunk z, output cols nh*128..+128. 4 waves.
__global__ __launch_bounds__(256)
void attn2_kernel(const unsigned short* __restrict__ qd16, const unsigned short* __restrict__ A16,
                  const unsigned short* __restrict__ kT16, const unsigned short* __restrict__ T16,
                  unsigned short* __restrict__ mo16) {
  __shared__ unsigned short As[64 * 64];    // 8KB
  __shared__ unsigned short Bs[128 * 64];   // 16KB
  const int tid = threadIdx.x, lane = tid & 63, wv = tid >> 6;
  const int nh = blockIdx.x, rh = blockIdx.y, z = blockIdx.z;
  const int roff = rh * 64;
  const int srow = tid >> 3, scol = (tid & 7) * 8;

  f32x4 acc[4][2] = {};
  const unsigned short* qz = qd16 + (long long)z * 32768 + (long long)roff * 256;  // [64][256]
  const unsigned short* Tz = T16 + (long long)z * 65536 + (long long)nh * 128 * 256;
  const unsigned short* Az = A16 + (long long)z * 16384 + (long long)roff * 128;   // [64][128]
  const unsigned short* kz = kT16 + (long long)z * 32768 + (long long)nh * 128 * 128;

  // ---- acc = qd @ T^T, K=256 ----
  for (int k0 = 0; k0 < 256; k0 += 64) {
    if (k0) __syncthreads();
#pragma unroll
    for (int i = 0; i < 2; i++) {
      int row = i * 32 + srow;
      GLD_LDS(qz + (long long)row * 256 + k0 + scol, &As[row * 64 + scol]);
    }
#pragma unroll
    for (int i = 0; i < 4; i++) {
      int row = i * 32 + srow;
      GLD_LDS(Tz + (long long)row * 256 + k0 + scol, &Bs[row * 64 + scol]);
    }
    __syncthreads();
#pragma unroll
    for (int kk = 0; kk < 2; kk++) {
      const int kb = kk * 32 + 8 * (lane >> 4);
      bf16x8 af[4], bfr[2];
#pragma unroll
      for (int m = 0; m < 4; m++)
        af[m] = *(const bf16x8*)&As[(m * 16 + (lane & 15)) * 64 + kb];
#pragma unroll
      for (int n = 0; n < 2; n++)
        bfr[n] = *(const bf16x8*)&Bs[(wv * 32 + n * 16 + (lane & 15)) * 64 + kb];
#pragma unroll
      for (int m = 0; m < 4; m++)
#pragma unroll
        for (int n = 0; n < 2; n++)
          acc[m][n] = __builtin_amdgcn_mfma_f32_16x16x32_bf16(af[m], bfr[n], acc[m][n], 0, 0, 0);
    }
  }

  // ---- acc += A @ kT^T, K=128 ----
  for (int k0 = 0; k0 < 128; k0 += 64) {
    __syncthreads();
#pragma unroll
    for (int i = 0; i < 2; i++) {
      int row = i * 32 + srow;
      GLD_LDS(Az + (long long)row * 128 + k0 + scol, &As[row * 64 + scol]);
    }
#pragma unroll
    for (int i = 0; i < 4; i++) {
      int row = i * 32 + srow;
      GLD_LDS(kz + (long long)row * 128 + k0 + scol, &Bs[row * 64 + scol]);
    }
    __syncthreads();
#pragma unroll
    for (int kk = 0; kk < 2; kk++) {
      const int kb = kk * 32 + 8 * (lane >> 4);
      bf16x8 af[4], bfr[2];
#pragma unroll
      for (int m = 0; m < 4; m++)
        af[m] = *(const bf16x8*)&As[(m * 16 + (lane & 15)) * 64 + kb];
#pragma unroll
      for (int n = 0; n < 2; n++)
        bfr[n] = *(const bf16x8*)&Bs[(wv * 32 + n * 16 + (lane & 15)) * 64 + kb];
#pragma unroll
      for (int m = 0; m < 4; m++)
#pragma unroll
        for (int n = 0; n < 2; n++)
          acc[m][n] = __builtin_amdgcn_mfma_f32_16x16x32_bf16(af[m], bfr[n], acc[m][n], 0, 0, 0);
    }
  }

  // ---- store mo ----
#pragma unroll
  for (int m = 0; m < 4; m++) {
#pragma unroll
    for (int n = 0; n < 2; n++) {
      int col = nh * 128 + wv * 32 + n * 16 + (lane & 15);
#pragma unroll
      for (int q = 0; q < 4; q++) {
        int row = roff + m * 16 + (lane >> 4) * 4 + q;
        mo16[((long long)z * 128 + row) * 256 + col] = f2bf(acc[m][n][q]);
      }
    }
  }
}

// ---------------------------------------------------------------- y GEMM (64x64 tile)
// out_y[8192][1024] = mo16[8192][256] @ wot16[1024][256]^T + bo. Grid 2048, XCD-swizzled.
__global__ __launch_bounds__(256)
void y64_kernel(const unsigned short* __restrict__ mo16, const unsigned short* __restrict__ wot16,
                const float* __restrict__ bo, float* __restrict__ out_y) {
  __shared__ unsigned short As[64 * 64];    // 8KB
  __shared__ unsigned short Bs[64 * 64];    // 8KB
  const int tid = threadIdx.x;
  const int bid = (blockIdx.x & 7) * (gridDim.x >> 3) + (blockIdx.x >> 3);
  const int bn = bid & 15, bm = bid >> 4;
  const int m0 = bm * 64, n0 = bn * 64;
  const int lane = tid & 63, wv = tid >> 6;
  const int srow = tid >> 3, scol = (tid & 7) * 8;

  f32x4 acc[4] = {};
  const unsigned short* Abase = mo16 + (long long)m0 * 256;
  const unsigned short* Bbase = wot16 + (long long)n0 * 256;

  for (int k0 = 0; k0 < 256; k0 += 64) {
    if (k0) __syncthreads();
#pragma unroll
    for (int i = 0; i < 2; i++) {
      int row = i * 32 + srow;
      GLD_LDS(Abase + (long long)row * 256 + k0 + scol, &As[row * 64 + scol]);
      GLD_LDS(Bbase + (long long)row * 256 + k0 + scol, &Bs[row * 64 + scol]);
    }
    __syncthreads();
#pragma unroll
    for (int kk = 0; kk < 2; kk++) {
      const int kb = kk * 32 + 8 * (lane >> 4);
      bf16x8 bfr = *(const bf16x8*)&Bs[(wv * 16 + (lane & 15)) * 64 + kb];
#pragma unroll
      for (int m = 0; m < 4; m++) {
        bf16x8 af = *(const bf16x8*)&As[(m * 16 + (lane & 15)) * 64 + kb];
        acc[m] = __builtin_amdgcn_mfma_f32_16x16x32_bf16(af, bfr, acc[m], 0, 0, 0);
      }
    }
  }

  const int col = n0 + wv * 16 + (lane & 15);
  const float b = bo[col];
#pragma unroll
  for (int m = 0; m < 4; m++) {
#pragma unroll
    for (int q = 0; q < 4; q++) {
      int row = m0 + m * 16 + (lane >> 4) * 4 + q;
      out_y[(long long)row * 1024 + col] = acc[m][q] + b;
    }
  }
}

// ---------------------------------------------------------------- prep (cast+gate+weight transposes)
__global__ __launch_bounds__(256)
void prep_kernel(const float* __restrict__ x, const float* __restrict__ Wg,
                 const float* __restrict__ bg, unsigned short* __restrict__ x16,
                 float* __restrict__ g,
                 const float* __restrict__ Wk, const float* __restrict__ Wv,
                 const float* __restrict__ Wq, unsigned short* __restrict__ w16,
                 const float* __restrict__ Wo, unsigned short* __restrict__ wot16) {
  __shared__ float tile[64][65];
  const int bx = blockIdx.x;
  const int tid = threadIdx.x;
  if (bx < 2048) {
    const int wave = tid >> 6, lane = tid & 63;
    const long long row = (long long)bx * 4 + wave;
    const float* xr = x + row * 1024 + lane * 16;
    const float* wr = Wg + lane * 16;
    float s = 0.f;
    u16x8 o0, o1;
#pragma unroll
    for (int qq = 0; qq < 2; qq++) {
      float4 a = *(const float4*)(xr + qq * 4);
      float4 w = *(const float4*)(wr + qq * 4);
      s = fmaf(a.x, w.x, s); s = fmaf(a.y, w.y, s);
      s = fmaf(a.z, w.z, s); s = fmaf(a.w, w.w, s);
      o0[qq * 4 + 0] = f2bf(a.x); o0[qq * 4 + 1] = f2bf(a.y);
      o0[qq * 4 + 2] = f2bf(a.z); o0[qq * 4 + 3] = f2bf(a.w);
    }
#pragma unroll
    for (int qq = 0; qq < 2; qq++) {
      float4 a = *(const float4*)(xr + 8 + qq * 4);
      float4 w = *(const float4*)(wr + 8 + qq * 4);
      s = fmaf(a.x, w.x, s); s = fmaf(a.y, w.y, s);
      s = fmaf(a.z, w.z, s); s = fmaf(a.w, w.w, s);
      o1[qq * 4 + 0] = f2bf(a.x); o1[qq * 4 + 1] = f2bf(a.y);
      o1[qq * 4 + 2] = f2bf(a.z); o1[qq * 4 + 3] = f2bf(a.w);
    }
    *(u16x8*)(x16 + row * 1024 + lane * 16) = o0;
    *(u16x8*)(x16 + row * 1024 + lane * 16 + 8) = o1;
#pragma unroll
    for (int off = 32; off; off >>= 1) s += __shfl_xor(s, off, 64);
    if (lane == 0) g[row] = 1.f / (1.f + expf(-(s + bg[0])));
    return;
  }
  int t = bx - 2048;
  const float* S; unsigned short* dst;
  int srcCols, dstLd, k0, n0g, n0;
  if (t < 192) {
    k0 = (t % 16) * 64; n0g = (t / 16) * 64;
    int sel = n0g >> 8; n0 = n0g - (sel << 8);
    S = sel == 0 ? Wk : sel == 1 ? Wv : Wq;
    srcCols = 256; dst = w16; dstLd = 1024;
  } else {
    t -= 192;
    k0 = (t % 4) * 64; n0g = (t / 4) * 64; n0 = n0g;
    S = Wo; srcCols = 1024; dst = wot16; dstLd = 256;
  }
  const int rr = tid >> 4, c4 = (tid & 15) * 4;
#pragma unroll
  for (int pp = 0; pp < 4; pp++) {
    int r = pp * 16 + rr;
    float4 v = *(const float4*)&S[(long long)(k0 + r) * srcCols + n0 + c4];
    tile[r][c4 + 0] = v.x; tile[r][c4 + 1] = v.y; tile[r][c4 + 2] = v.z; tile[r][c4 + 3] = v.w;
  }
  __syncthreads();
  const int rn = tid >> 3, ck0 = (tid & 7) * 8;
#pragma unroll
  for (int pp = 0; pp < 2; pp++) {
    int n = pp * 32 + rn;
    u16x8 o;
#pragma unroll
    for (int j = 0; j < 8; j++) o[j] = f2bf(tile[ck0 + j][n]);
    *(u16x8*)&dst[(long long)(n0g + n) * dstLd + k0 + ck0] = o;
  }
}

// ---------------------------------------------------------------- chunk-state scan (x8 vectorized)
__global__ __launch_bounds__(256)
void scan_kernel(const unsigned short* __restrict__ Ut16, const float* __restrict__ state_in,
                 unsigned short* __restrict__ T16, float* __restrict__ final_out,
                 const float* __restrict__ decay_ptr) {
  int t = blockIdx.x * 256 + threadIdx.x;   // 0..32767
  int p0 = t * 8;
  int b = p0 >> 16, pbase = p0 & 65535;     // pidx = e*256+d
  float dC = exp2f(128.f * log2f(decay_ptr[0]));
  float cur[8];
#pragma unroll
  for (int h = 0; h < 8; h++) {
    int pidx = pbase + h;
    int e = pidx >> 8, d = pidx & 255;
    cur[h] = state_in[(long long)b * 65536 + d * 256 + e];
  }
#pragma unroll
  for (int c = 0; c < 16; c++) {
    long long off = ((long long)(b * 16 + c)) * 65536 + pbase;
    u16x8 uin = *(const u16x8*)&Ut16[off];
    u16x8 tout;
#pragma unroll
    for (int h = 0; h < 8; h++) {
      tout[h] = f2bf(cur[h]);
      cur[h] = fmaf(dC, cur[h], bf2f(uin[h]));
    }
    *(u16x8*)&T16[off] = tout;
  }
#pragma unroll
  for (int h = 0; h < 8; h++) {
    int pidx = pbase + h;
    int e = pidx >> 8, d = pidx & 255;
    final_out[(long long)b * 65536 + d * 256 + e] = cur[h];
  }
}

// ---------------------------------------------------------------- launch
extern "C" void kernel_launch(void* const* d_in, const int* in_sizes, int n_in,
                              void* d_out, int out_size, void* d_ws, size_t ws_size,
                              hipStream_t stream) {
  const float* x     = (const float*)d_in[0];
  const float* state = (const float*)d_in[1];
  const float* Wk = (const float*)d_in[2];  const float* bk = (const float*)d_in[3];
  const float* Wv = (const float*)d_in[4];  const float* bv = (const float*)d_in[5];
  const float* Wq = (const float*)d_in[6];  const float* bq = (const float*)d_in[7];
  const float* Wo = (const float*)d_in[8];  const float* bo = (const float*)d_in[9];
  const float* Wg = (const float*)d_in[10]; const float* bg = (const float*)d_in[11];
  const float* decay = (const float*)d_in[12];

  float* out_y = (float*)d_out;              // [4][2048][1024]
  float* out_S = out_y + 8388608;            // [4][256][256]

  float* ws = (float*)d_ws;
  unsigned short* x16   = (unsigned short*)(ws);             // [8192][1024]
  unsigned short* v16   = (unsigned short*)(ws + 4194304);   // [8192][256]
  unsigned short* qd16  = (unsigned short*)(ws + 5242880);   // [8192][256] (q * d^i)
  unsigned short* w16   = (unsigned short*)(ws + 6291456);   // [768][1024]
  unsigned short* wot16 = (unsigned short*)(ws + 6684672);   // [1024][256]
  float*          gbuf  = ws + 6815744;                      // [8192]
  unsigned short* kT16  = (unsigned short*)(ws + 6823936);   // [64][256][128]
  unsigned short* vTw16 = (unsigned short*)(ws + 7872512);   // [64][256][128]
  unsigned short* Ut16  = (unsigned short*)(ws + 8921088);   // [64][256][256]
  unsigned short* T16   = (unsigned short*)(ws + 11018240);  // [64][256][256]
  unsigned short* mo16  = (unsigned short*)(ws + 13115392);  // [8192][256]
  unsigned short* A16   = (unsigned short*)(ws + 14163968);  // [64][128][128]

  // 1. prep: cast+gate + weight transposes
  prep_kernel<<<2304, 256, 0, stream>>>(x, Wg, bg, x16, gbuf, Wk, Wv, Wq, w16, Wo, wot16);

  // 2. proj (64x64 tiles, BK=64, 1536 blocks, XCD-swizzled)
  proj_kernel<<<1536, 256, 0, stream>>>(x16, w16, bk, bv, bq, gbuf, decay,
                                        v16, qd16, kT16, vTw16);

  // 3. mid: Ut quadrants (256 blocks) + scores (64 blocks), one launch
  mid_kernel<<<320, 256, 0, stream>>>(kT16, vTw16, Ut16, qd16, v16, A16, gbuf, decay);

  // 4. chunk-state scan -> T16 + final_state
  scan_kernel<<<128, 256, 0, stream>>>(Ut16, state, T16, out_S, decay);

  // 5. attn2: mo = qd@T^T + A@kT^T
  attn2_kernel<<<dim3(2, 2, 64), 256, 0, stream>>>(qd16, A16, kT16, T16, mo16);

  // 6. y = mo16 @ wot16^T + bo  (64x64 tiles, 2048 blocks, XCD-swizzled)
  y64_kernel<<<2048, 256, 0, stream>>>(mo16, wot16, bo, out_y);
}

// Round 15
// 79.946 us; speedup vs baseline: 1.1197x; 1.1197x over previous
//
#include <hip/hip_runtime.h>
#include <math.h>

// NeuralMemory: chunked-parallel decaying rank-1 memory scan, all-MFMA version.
//   S_t = decay*S_{t-1} + s_t * v_t k_t^T ;  out_t = q_t^T S_{t-1}
// Chunk C=128, NC=16, b=4, s=2048, d_model=1024, d_mem=256.
//
//  1. prep:   x -> x16 ; gate = sigmoid(x@Wg+bg) ; Wk|Wv|Wq -> w16 ; Wo -> wot16
//  2. proj:   64x128-tile MFMA, BK=64 (768 blocks, 3/CU): v16, qd16 = bf16(x@W + b);
//             epilogue LDS-transposes k/v half-tiles -> kT16/vTw16 (gate-folded)
//  3. mid:    ONE launch, 320 blocks: [0,256) Ut16[z] quadrants = kT @ vTw^T;
//             [256,320) scores A16[z] = mask(qd@v^T)*gate  (independent work overlapped)
//  4. scan:   T16[z] = bf16(S_c^T) running over chunks; writes final_state (x8 vectorized)
//  5. attn2:  mo16 = qd@T^T + A16@kT^T   (per nh,rh,z; 256 blocks)
//  6. y64:    64x128-tile MFMA (1024 blocks, 4/CU): out_y = mo16 @ wot16^T + bo

using bf16x8 = __attribute__((ext_vector_type(8))) short;
using f32x4  = __attribute__((ext_vector_type(4))) float;
using u16x4  = __attribute__((ext_vector_type(4))) unsigned short;
using u16x8  = __attribute__((ext_vector_type(8))) unsigned short;

__device__ inline unsigned short f2bf(float f) {
  unsigned int u = __float_as_uint(f);
  u = (u + 0x7FFF + ((u >> 16) & 1)) >> 16;
  return (unsigned short)u;
}
__device__ inline float bf2f(unsigned short u) {
  return __uint_as_float(((unsigned int)u) << 16);
}

#define GLD_LDS(gsrc, ldst) \
  __builtin_amdgcn_global_load_lds( \
      (const __attribute__((address_space(1))) unsigned int*)(gsrc), \
      (__attribute__((address_space(3))) unsigned int*)(ldst), 16, 0, 0)

// ---------------------------------------------------------------- proj (64x128 tile, BK=64)
// Grid 768 (XCD-swizzled): bn in [0,6) selects k/v/q + 128-col half; bm in [0,128)
// is a 64-row slab (chunk z = bm>>1, j-half = bm&1). 4 waves, wave cols wv*32..+32.
__global__ __launch_bounds__(256)
void proj_kernel(const unsigned short* __restrict__ x16, const unsigned short* __restrict__ w16,
                 const float* __restrict__ bk, const float* __restrict__ bv,
                 const float* __restrict__ bq, const float* __restrict__ gate,
                 const float* __restrict__ decay_ptr,
                 unsigned short* __restrict__ o_v, unsigned short* __restrict__ o_qd,
                 unsigned short* __restrict__ o_kT, unsigned short* __restrict__ o_vTw) {
  __shared__ unsigned short As[64 * 64];    // 8KB
  __shared__ unsigned short Bs[128 * 64];   // 16KB; reused as 128x64 transpose buf
  __shared__ float warr[64];
  const int tid = threadIdx.x;
  const int bid = (blockIdx.x & 7) * (gridDim.x >> 3) + (blockIdx.x >> 3);
  const int bn = bid % 6, bm = bid / 6;
  const int m0 = bm * 64, n0 = bn * 128;
  const int lane = tid & 63, wv = tid >> 6;
  const int srow = tid >> 3, scol = (tid & 7) * 8;   // srow 0..31

  f32x4 acc[4][2] = {};
  const unsigned short* Abase = x16 + (long long)m0 * 1024;
  const unsigned short* Bbase = w16 + (long long)n0 * 1024;

  for (int k0 = 0; k0 < 1024; k0 += 64) {
    if (k0) __syncthreads();
#pragma unroll
    for (int i = 0; i < 2; i++) {
      int row = i * 32 + srow;
      GLD_LDS(Abase + (long long)row * 1024 + k0 + scol, &As[row * 64 + scol]);
    }
#pragma unroll
    for (int i = 0; i < 4; i++) {
      int row = i * 32 + srow;
      GLD_LDS(Bbase + (long long)row * 1024 + k0 + scol, &Bs[row * 64 + scol]);
    }
    __syncthreads();
#pragma unroll
    for (int kk = 0; kk < 2; kk++) {
      const int kb = kk * 32 + 8 * (lane >> 4);
      bf16x8 af[4], bfr[2];
#pragma unroll
      for (int m = 0; m < 4; m++)
        af[m] = *(const bf16x8*)&As[(m * 16 + (lane & 15)) * 64 + kb];
#pragma unroll
      for (int n = 0; n < 2; n++)
        bfr[n] = *(const bf16x8*)&Bs[(wv * 32 + n * 16 + (lane & 15)) * 64 + kb];
#pragma unroll
      for (int m = 0; m < 4; m++)
#pragma unroll
        for (int n = 0; n < 2; n++)
          acc[m][n] = __builtin_amdgcn_mfma_f32_16x16x32_bf16(af[m], bfr[n], acc[m][n], 0, 0, 0);
    }
  }

  const float log2d = log2f(decay_ptr[0]);
  const int sel = bn >> 1;        // 0:k 1:v 2:q
  const int half = bn & 1;        // 128-col half of d_mem
  const int z = bm >> 1, jbase = (bm & 1) * 64;

  if (sel < 2) {
    __syncthreads();              // all waves done with As/Bs fragments
    if (sel == 1 && tid < 64)
      warr[tid] = gate[z * 128 + jbase + tid] * exp2f((float)(127 - (jbase + tid)) * log2d);
  }

#pragma unroll
  for (int m = 0; m < 4; m++) {
#pragma unroll
    for (int n = 0; n < 2; n++) {
      int cl = wv * 32 + n * 16 + (lane & 15);   // local col 0..127
      int r0 = m * 16 + (lane >> 4) * 4;         // local row base 0..63
      float bias = (sel == 0) ? bk[half * 128 + cl]
                 : (sel == 1) ? bv[half * 128 + cl]
                 : bq[half * 128 + cl];
      if (sel < 2) {
        u16x4 pk;
#pragma unroll
        for (int q = 0; q < 4; q++) {
          float v = acc[m][n][q] + bias;
          pk[q] = f2bf(v);
          if (sel == 1)
            o_v[((long long)m0 + r0 + q) * 256 + half * 128 + cl] = pk[q];
        }
        int byteoff = (cl * 128 + r0 * 2) ^ ((cl & 7) << 4);
        *(u16x4*)((char*)Bs + byteoff) = pk;
      } else {
#pragma unroll
        for (int q = 0; q < 4; q++) {
          long long row = m0 + r0 + q;
          float v = acc[m][n][q] + bias;
          o_qd[row * 256 + half * 128 + cl] =
              f2bf(v * exp2f((float)(jbase + r0 + q) * log2d));
        }
      }
    }
  }

  if (sel < 2) {
    __syncthreads();
    unsigned short* dst = (sel == 0 ? o_kT : o_vTw) + (long long)z * 32768;
#pragma unroll
    for (int pp = 0; pp < 4; pp++) {
      int idx = pp * 256 + tid;    // 0..1023
      int c = idx >> 3;            // local col (d) 0..127
      int j0 = (idx & 7) * 8;      // row-run start 0..56
      u16x8 o = *(const u16x8*)((char*)Bs + ((c * 128 + j0 * 2) ^ ((c & 7) << 4)));
      if (sel == 1) {
#pragma unroll
        for (int t = 0; t < 8; t++) o[t] = f2bf(bf2f(o[t]) * warr[j0 + t]);
      }
      *(u16x8*)&dst[(long long)(half * 128 + c) * 128 + jbase + j0] = o;
    }
  }
}

// ---------------------------------------------------------------- mid: Ut quadrants + scores
// Grid 320 x 256thr. bid<256: Ut quadrant (z=bid>>2, bm=(bid>>1)&1, bn=bid&1).
// bid>=256: scores chunk z=bid-256: A16[z][i][j] = (i>j) ? (qd_i.v_j)*s_j*d^{-(j+1)} : 0.
__global__ __launch_bounds__(256)
void mid_kernel(const unsigned short* __restrict__ kT16, const unsigned short* __restrict__ vTw16,
                unsigned short* __restrict__ Ut16,
                const unsigned short* __restrict__ qd16, const unsigned short* __restrict__ v16,
                unsigned short* __restrict__ A16, const float* __restrict__ gbuf,
                const float* __restrict__ decay_ptr) {
  __shared__ unsigned short As[128 * 64];
  __shared__ unsigned short Bs[128 * 64];
  const int tid = threadIdx.x, lane = tid & 63, wv = tid >> 6;
  const int wr = wv >> 1, wc = wv & 1;
  const int srow = tid >> 3, scol = (tid & 7) * 8;
  f32x4 acc[4][4] = {};

  if (blockIdx.x < 256) {
    // ---------------- Ut quadrant ----------------
    const int b = blockIdx.x;
    const int z = b >> 2, bm = (b >> 1) & 1, bn = b & 1;
    const unsigned short* Abase = kT16 + (long long)z * 32768 + (long long)(bm * 128) * 128;
    const unsigned short* Bbase = vTw16 + (long long)z * 32768 + (long long)(bn * 128) * 128;
    for (int k0 = 0; k0 < 128; k0 += 64) {
      if (k0) __syncthreads();
#pragma unroll
      for (int i = 0; i < 4; i++) {
        int row = i * 32 + srow;
        GLD_LDS(Abase + (long long)row * 128 + k0 + scol, &As[row * 64 + scol]);
        GLD_LDS(Bbase + (long long)row * 128 + k0 + scol, &Bs[row * 64 + scol]);
      }
      __syncthreads();
#pragma unroll
      for (int kk = 0; kk < 2; kk++) {
        const int kb = kk * 32 + 8 * (lane >> 4);
        bf16x8 af[4], bfr[4];
#pragma unroll
        for (int m = 0; m < 4; m++)
          af[m] = *(const bf16x8*)&As[(wr * 64 + m * 16 + (lane & 15)) * 64 + kb];
#pragma unroll
        for (int n = 0; n < 4; n++)
          bfr[n] = *(const bf16x8*)&Bs[(wc * 64 + n * 16 + (lane & 15)) * 64 + kb];
#pragma unroll
        for (int m = 0; m < 4; m++)
#pragma unroll
          for (int n = 0; n < 4; n++)
            acc[m][n] = __builtin_amdgcn_mfma_f32_16x16x32_bf16(af[m], bfr[n], acc[m][n], 0, 0, 0);
      }
    }
    unsigned short* out = Ut16 + (long long)z * 65536;
#pragma unroll
    for (int m = 0; m < 4; m++) {
#pragma unroll
      for (int n = 0; n < 4; n++) {
        int col = bn * 128 + wc * 64 + n * 16 + (lane & 15);
#pragma unroll
        for (int q = 0; q < 4; q++) {
          int row = bm * 128 + wr * 64 + m * 16 + (lane >> 4) * 4 + q;
          out[(long long)row * 256 + col] = f2bf(acc[m][n][q]);
        }
      }
    }
  } else {
    // ---------------- scores ----------------
    const int z = blockIdx.x - 256;
    const unsigned short* Abase = qd16 + (long long)z * 32768;   // [128][256]
    const unsigned short* Bbase = v16 + (long long)z * 32768;
    for (int k0 = 0; k0 < 256; k0 += 64) {
      if (k0) __syncthreads();
#pragma unroll
      for (int i = 0; i < 4; i++) {
        int row = i * 32 + srow;
        GLD_LDS(Abase + (long long)row * 256 + k0 + scol, &As[row * 64 + scol]);
        GLD_LDS(Bbase + (long long)row * 256 + k0 + scol, &Bs[row * 64 + scol]);
      }
      __syncthreads();
#pragma unroll
      for (int kk = 0; kk < 2; kk++) {
        const int kb = kk * 32 + 8 * (lane >> 4);
        bf16x8 af[4], bfr[4];
#pragma unroll
        for (int m = 0; m < 4; m++)
          af[m] = *(const bf16x8*)&As[(wr * 64 + m * 16 + (lane & 15)) * 64 + kb];
#pragma unroll
        for (int n = 0; n < 4; n++)
          bfr[n] = *(const bf16x8*)&Bs[(wc * 64 + n * 16 + (lane & 15)) * 64 + kb];
#pragma unroll
        for (int m = 0; m < 4; m++)
#pragma unroll
          for (int n = 0; n < 4; n++)
            acc[m][n] = __builtin_amdgcn_mfma_f32_16x16x32_bf16(af[m], bfr[n], acc[m][n], 0, 0, 0);
      }
    }
    const float log2d = log2f(decay_ptr[0]);
    unsigned short* out = A16 + (long long)z * 16384;
#pragma unroll
    for (int n = 0; n < 4; n++) {
      int col = wc * 64 + n * 16 + (lane & 15);       // j
      float gsc = gbuf[z * 128 + col] * exp2f(-(float)(col + 1) * log2d);
#pragma unroll
      for (int m = 0; m < 4; m++) {
#pragma unroll
        for (int q = 0; q < 4; q++) {
          int row = wr * 64 + m * 16 + (lane >> 4) * 4 + q;   // i
          float v = (col < row) ? acc[m][n][q] * gsc : 0.f;
          out[(long long)row * 128 + col] = f2bf(v);
        }
      }
    }
  }
}

// ---------------------------------------------------------------- attn2: mo = qd@T^T + A@kT^T
// Block (nh, rh, z): rows roff..roff+64 of chunk z, output cols nh*128..+128. 4 waves.
__global__ __launch_bounds__(256)
void attn2_kernel(const unsigned short* __restrict__ qd16, const unsigned short* __restrict__ A16,
                  const unsigned short* __restrict__ kT16, const unsigned short* __restrict__ T16,
                  unsigned short* __restrict__ mo16) {
  __shared__ unsigned short As[64 * 64];    // 8KB
  __shared__ unsigned short Bs[128 * 64];   // 16KB
  const int tid = threadIdx.x, lane = tid & 63, wv = tid >> 6;
  const int nh = blockIdx.x, rh = blockIdx.y, z = blockIdx.z;
  const int roff = rh * 64;
  const int srow = tid >> 3, scol = (tid & 7) * 8;

  f32x4 acc[4][2] = {};
  const unsigned short* qz = qd16 + (long long)z * 32768 + (long long)roff * 256;  // [64][256]
  const unsigned short* Tz = T16 + (long long)z * 65536 + (long long)nh * 128 * 256;
  const unsigned short* Az = A16 + (long long)z * 16384 + (long long)roff * 128;   // [64][128]
  const unsigned short* kz = kT16 + (long long)z * 32768 + (long long)nh * 128 * 128;

  // ---- acc = qd @ T^T, K=256 ----
  for (int k0 = 0; k0 < 256; k0 += 64) {
    if (k0) __syncthreads();
#pragma unroll
    for (int i = 0; i < 2; i++) {
      int row = i * 32 + srow;
      GLD_LDS(qz + (long long)row * 256 + k0 + scol, &As[row * 64 + scol]);
    }
#pragma unroll
    for (int i = 0; i < 4; i++) {
      int row = i * 32 + srow;
      GLD_LDS(Tz + (long long)row * 256 + k0 + scol, &Bs[row * 64 + scol]);
    }
    __syncthreads();
#pragma unroll
    for (int kk = 0; kk < 2; kk++) {
      const int kb = kk * 32 + 8 * (lane >> 4);
      bf16x8 af[4], bfr[2];
#pragma unroll
      for (int m = 0; m < 4; m++)
        af[m] = *(const bf16x8*)&As[(m * 16 + (lane & 15)) * 64 + kb];
#pragma unroll
      for (int n = 0; n < 2; n++)
        bfr[n] = *(const bf16x8*)&Bs[(wv * 32 + n * 16 + (lane & 15)) * 64 + kb];
#pragma unroll
      for (int m = 0; m < 4; m++)
#pragma unroll
        for (int n = 0; n < 2; n++)
          acc[m][n] = __builtin_amdgcn_mfma_f32_16x16x32_bf16(af[m], bfr[n], acc[m][n], 0, 0, 0);
    }
  }

  // ---- acc += A @ kT^T, K=128 ----
  for (int k0 = 0; k0 < 128; k0 += 64) {
    __syncthreads();
#pragma unroll
    for (int i = 0; i < 2; i++) {
      int row = i * 32 + srow;
      GLD_LDS(Az + (long long)row * 128 + k0 + scol, &As[row * 64 + scol]);
    }
#pragma unroll
    for (int i = 0; i < 4; i++) {
      int row = i * 32 + srow;
      GLD_LDS(kz + (long long)row * 128 + k0 + scol, &Bs[row * 64 + scol]);
    }
    __syncthreads();
#pragma unroll
    for (int kk = 0; kk < 2; kk++) {
      const int kb = kk * 32 + 8 * (lane >> 4);
      bf16x8 af[4], bfr[2];
#pragma unroll
      for (int m = 0; m < 4; m++)
        af[m] = *(const bf16x8*)&As[(m * 16 + (lane & 15)) * 64 + kb];
#pragma unroll
      for (int n = 0; n < 2; n++)
        bfr[n] = *(const bf16x8*)&Bs[(wv * 32 + n * 16 + (lane & 15)) * 64 + kb];
#pragma unroll
      for (int m = 0; m < 4; m++)
#pragma unroll
        for (int n = 0; n < 2; n++)
          acc[m][n] = __builtin_amdgcn_mfma_f32_16x16x32_bf16(af[m], bfr[n], acc[m][n], 0, 0, 0);
    }
  }

  // ---- store mo ----
#pragma unroll
  for (int m = 0; m < 4; m++) {
#pragma unroll
    for (int n = 0; n < 2; n++) {
      int col = nh * 128 + wv * 32 + n * 16 + (lane & 15);
#pragma unroll
      for (int q = 0; q < 4; q++) {
        int row = roff + m * 16 + (lane >> 4) * 4 + q;
        mo16[((long long)z * 128 + row) * 256 + col] = f2bf(acc[m][n][q]);
      }
    }
  }
}

// ---------------------------------------------------------------- y GEMM (64x128 tile)
__global__ __launch_bounds__(256)
void y64_kernel(const unsigned short* __restrict__ mo16, const unsigned short* __restrict__ wot16,
                const float* __restrict__ bo, float* __restrict__ out_y) {
  __shared__ unsigned short As[64 * 64];    // 8KB
  __shared__ unsigned short Bs[128 * 64];   // 16KB
  const int tid = threadIdx.x;
  const int bid = (blockIdx.x & 7) * (gridDim.x >> 3) + (blockIdx.x >> 3);
  const int bn = bid & 7, bm = bid >> 3;
  const int m0 = bm * 64, n0 = bn * 128;
  const int lane = tid & 63, wv = tid >> 6;
  const int srow = tid >> 3, scol = (tid & 7) * 8;

  f32x4 acc[4][2] = {};
  const unsigned short* Abase = mo16 + (long long)m0 * 256;
  const unsigned short* Bbase = wot16 + (long long)n0 * 256;

  for (int k0 = 0; k0 < 256; k0 += 64) {
    if (k0) __syncthreads();
#pragma unroll
    for (int i = 0; i < 2; i++) {
      int row = i * 32 + srow;
      GLD_LDS(Abase + (long long)row * 256 + k0 + scol, &As[row * 64 + scol]);
    }
#pragma unroll
    for (int i = 0; i < 4; i++) {
      int row = i * 32 + srow;
      GLD_LDS(Bbase + (long long)row * 256 + k0 + scol, &Bs[row * 64 + scol]);
    }
    __syncthreads();
#pragma unroll
    for (int kk = 0; kk < 2; kk++) {
      const int kb = kk * 32 + 8 * (lane >> 4);
      bf16x8 af[4], bfr[2];
#pragma unroll
      for (int m = 0; m < 4; m++)
        af[m] = *(const bf16x8*)&As[(m * 16 + (lane & 15)) * 64 + kb];
#pragma unroll
      for (int n = 0; n < 2; n++)
        bfr[n] = *(const bf16x8*)&Bs[(wv * 32 + n * 16 + (lane & 15)) * 64 + kb];
#pragma unroll
      for (int m = 0; m < 4; m++)
#pragma unroll
        for (int n = 0; n < 2; n++)
          acc[m][n] = __builtin_amdgcn_mfma_f32_16x16x32_bf16(af[m], bfr[n], acc[m][n], 0, 0, 0);
    }
  }

#pragma unroll
  for (int m = 0; m < 4; m++) {
#pragma unroll
    for (int n = 0; n < 2; n++) {
      int col = n0 + wv * 32 + n * 16 + (lane & 15);
      float b = bo[col];
#pragma unroll
      for (int q = 0; q < 4; q++) {
        int row = m0 + m * 16 + (lane >> 4) * 4 + q;
        out_y[(long long)row * 1024 + col] = acc[m][n][q] + b;
      }
    }
  }
}

// ---------------------------------------------------------------- prep (cast+gate+weight transposes)
__global__ __launch_bounds__(256)
void prep_kernel(const float* __restrict__ x, const float* __restrict__ Wg,
                 const float* __restrict__ bg, unsigned short* __restrict__ x16,
                 float* __restrict__ g,
                 const float* __restrict__ Wk, const float* __restrict__ Wv,
                 const float* __restrict__ Wq, unsigned short* __restrict__ w16,
                 const float* __restrict__ Wo, unsigned short* __restrict__ wot16) {
  __shared__ float tile[64][65];
  const int bx = blockIdx.x;
  const int tid = threadIdx.x;
  if (bx < 2048) {
    const int wave = tid >> 6, lane = tid & 63;
    const long long row = (long long)bx * 4 + wave;
    const float* xr = x + row * 1024 + lane * 16;
    const float* wr = Wg + lane * 16;
    float s = 0.f;
    u16x8 o0, o1;
#pragma unroll
    for (int qq = 0; qq < 2; qq++) {
      float4 a = *(const float4*)(xr + qq * 4);
      float4 w = *(const float4*)(wr + qq * 4);
      s = fmaf(a.x, w.x, s); s = fmaf(a.y, w.y, s);
      s = fmaf(a.z, w.z, s); s = fmaf(a.w, w.w, s);
      o0[qq * 4 + 0] = f2bf(a.x); o0[qq * 4 + 1] = f2bf(a.y);
      o0[qq * 4 + 2] = f2bf(a.z); o0[qq * 4 + 3] = f2bf(a.w);
    }
#pragma unroll
    for (int qq = 0; qq < 2; qq++) {
      float4 a = *(const float4*)(xr + 8 + qq * 4);
      float4 w = *(const float4*)(wr + 8 + qq * 4);
      s = fmaf(a.x, w.x, s); s = fmaf(a.y, w.y, s);
      s = fmaf(a.z, w.z, s); s = fmaf(a.w, w.w, s);
      o1[qq * 4 + 0] = f2bf(a.x); o1[qq * 4 + 1] = f2bf(a.y);
      o1[qq * 4 + 2] = f2bf(a.z); o1[qq * 4 + 3] = f2bf(a.w);
    }
    *(u16x8*)(x16 + row * 1024 + lane * 16) = o0;
    *(u16x8*)(x16 + row * 1024 + lane * 16 + 8) = o1;
#pragma unroll
    for (int off = 32; off; off >>= 1) s += __shfl_xor(s, off, 64);
    if (lane == 0) g[row] = 1.f / (1.f + expf(-(s + bg[0])));
    return;
  }
  int t = bx - 2048;
  const float* S; unsigned short* dst;
  int srcCols, dstLd, k0, n0g, n0;
  if (t < 192) {
    k0 = (t % 16) * 64; n0g = (t / 16) * 64;
    int sel = n0g >> 8; n0 = n0g - (sel << 8);
    S = sel == 0 ? Wk : sel == 1 ? Wv : Wq;
    srcCols = 256; dst = w16; dstLd = 1024;
  } else {
    t -= 192;
    k0 = (t % 4) * 64; n0g = (t / 4) * 64; n0 = n0g;
    S = Wo; srcCols = 1024; dst = wot16; dstLd = 256;
  }
  const int rr = tid >> 4, c4 = (tid & 15) * 4;
#pragma unroll
  for (int pp = 0; pp < 4; pp++) {
    int r = pp * 16 + rr;
    float4 v = *(const float4*)&S[(long long)(k0 + r) * srcCols + n0 + c4];
    tile[r][c4 + 0] = v.x; tile[r][c4 + 1] = v.y; tile[r][c4 + 2] = v.z; tile[r][c4 + 3] = v.w;
  }
  __syncthreads();
  const int rn = tid >> 3, ck0 = (tid & 7) * 8;
#pragma unroll
  for (int pp = 0; pp < 2; pp++) {
    int n = pp * 32 + rn;
    u16x8 o;
#pragma unroll
    for (int j = 0; j < 8; j++) o[j] = f2bf(tile[ck0 + j][n]);
    *(u16x8*)&dst[(long long)(n0g + n) * dstLd + k0 + ck0] = o;
  }
}

// ---------------------------------------------------------------- chunk-state scan (x8 vectorized)
// Thread handles 8 consecutive pidx. Grid 128 x 256.
__global__ __launch_bounds__(256)
void scan_kernel(const unsigned short* __restrict__ Ut16, const float* __restrict__ state_in,
                 unsigned short* __restrict__ T16, float* __restrict__ final_out,
                 const float* __restrict__ decay_ptr) {
  int t = blockIdx.x * 256 + threadIdx.x;   // 0..32767
  int p0 = t * 8;                           // 0..262136, within one b-plane (65536%8==0)
  int b = p0 >> 16, pbase = p0 & 65535;     // pidx = e*256+d
  float dC = exp2f(128.f * log2f(decay_ptr[0]));
  float cur[8];
#pragma unroll
  for (int h = 0; h < 8; h++) {
    int pidx = pbase + h;
    int e = pidx >> 8, d = pidx & 255;
    cur[h] = state_in[(long long)b * 65536 + d * 256 + e];
  }
#pragma unroll
  for (int c = 0; c < 16; c++) {
    long long off = ((long long)(b * 16 + c)) * 65536 + pbase;
    u16x8 uin = *(const u16x8*)&Ut16[off];
    u16x8 tout;
#pragma unroll
    for (int h = 0; h < 8; h++) {
      tout[h] = f2bf(cur[h]);
      cur[h] = fmaf(dC, cur[h], bf2f(uin[h]));
    }
    *(u16x8*)&T16[off] = tout;
  }
#pragma unroll
  for (int h = 0; h < 8; h++) {
    int pidx = pbase + h;
    int e = pidx >> 8, d = pidx & 255;
    final_out[(long long)b * 65536 + d * 256 + e] = cur[h];
  }
}

// ---------------------------------------------------------------- launch
extern "C" void kernel_launch(void* const* d_in, const int* in_sizes, int n_in,
                              void* d_out, int out_size, void* d_ws, size_t ws_size,
                              hipStream_t stream) {
  const float* x     = (const float*)d_in[0];
  const float* state = (const float*)d_in[1];
  const float* Wk = (const float*)d_in[2];  const float* bk = (const float*)d_in[3];
  const float* Wv = (const float*)d_in[4];  const float* bv = (const float*)d_in[5];
  const float* Wq = (const float*)d_in[6];  const float* bq = (const float*)d_in[7];
  const float* Wo = (const float*)d_in[8];  const float* bo = (const float*)d_in[9];
  const float* Wg = (const float*)d_in[10]; const float* bg = (const float*)d_in[11];
  const float* decay = (const float*)d_in[12];

  float* out_y = (float*)d_out;              // [4][2048][1024]
  float* out_S = out_y + 8388608;            // [4][256][256]

  float* ws = (float*)d_ws;
  unsigned short* x16   = (unsigned short*)(ws);             // [8192][1024]
  unsigned short* v16   = (unsigned short*)(ws + 4194304);   // [8192][256]
  unsigned short* qd16  = (unsigned short*)(ws + 5242880);   // [8192][256] (q * d^i)
  unsigned short* w16   = (unsigned short*)(ws + 6291456);   // [768][1024]
  unsigned short* wot16 = (unsigned short*)(ws + 6684672);   // [1024][256]
  float*          gbuf  = ws + 6815744;                      // [8192]
  unsigned short* kT16  = (unsigned short*)(ws + 6823936);   // [64][256][128]
  unsigned short* vTw16 = (unsigned short*)(ws + 7872512);   // [64][256][128]
  unsigned short* Ut16  = (unsigned short*)(ws + 8921088);   // [64][256][256]
  unsigned short* T16   = (unsigned short*)(ws + 11018240);  // [64][256][256]
  unsigned short* mo16  = (unsigned short*)(ws + 13115392);  // [8192][256]
  unsigned short* A16   = (unsigned short*)(ws + 14163968);  // [64][128][128]

  // 1. prep: cast+gate + weight transposes
  prep_kernel<<<2304, 256, 0, stream>>>(x, Wg, bg, x16, gbuf, Wk, Wv, Wq, w16, Wo, wot16);

  // 2. proj (64x128 tiles, BK=64, 768 blocks, XCD-swizzled)
  proj_kernel<<<768, 256, 0, stream>>>(x16, w16, bk, bv, bq, gbuf, decay,
                                       v16, qd16, kT16, vTw16);

  // 3. mid: Ut quadrants (256 blocks) + scores (64 blocks), one launch
  mid_kernel<<<320, 256, 0, stream>>>(kT16, vTw16, Ut16, qd16, v16, A16, gbuf, decay);

  // 4. chunk-state scan -> T16 + final_state
  scan_kernel<<<128, 256, 0, stream>>>(Ut16, state, T16, out_S, decay);

  // 5. attn2: mo = qd@T^T + A@kT^T
  attn2_kernel<<<dim3(2, 2, 64), 256, 0, stream>>>(qd16, A16, kT16, T16, mo16);

  // 6. y = mo16 @ wot16^T + bo  (64x128 tiles, 1024 blocks, XCD-swizzled)
  y64_kernel<<<1024, 256, 0, stream>>>(mo16, wot16, bo, out_y);
}